// Round 10
// baseline (110.698 us; speedup 1.0000x reference)
//
#include <hip/hip_runtime.h>
#include <math.h>

#define Bp 256
#define Tp 128
#define SDp 8
#define ADp 2
#define Hp 3
#define Kp 4
#define HIDp 256
#define QDp (SDp + ADp)       // 10
#define X1Dp (Hp * Kp + QDp)  // 22  (row padded to 32 bf16 = 64 B)
#define QKLD 17               // qk row stride (floats): 17*t%32 distinct -> conflict-free
#define LOG2E 1.4426950408889634f

typedef short bf16x8 __attribute__((ext_vector_type(8)));
typedef float f32x4  __attribute__((ext_vector_type(4)));

__device__ __forceinline__ unsigned short f2bf(float f) {
    unsigned u = __float_as_uint(f);
    unsigned r = (u + 0x7FFFu + ((u >> 16) & 1u)) >> 16;
    return (unsigned short)r;
}

// h1 LDS: row stride 512 B, XOR bits 4-6 with row&7 -> conflict-free b128 col reads
__device__ __forceinline__ unsigned h1_byte(int row, int colbytes) {
    return (((unsigned)row << 9) + (unsigned)colbytes) ^ ((unsigned)(row & 7) << 4);
}
// X1s LDS: row stride 64 B, XOR byte 4-5 with row bits 1-2 -> conflict-free b128 A reads
__device__ __forceinline__ unsigned x1_byte(int row, int colbytes) {
    return ((unsigned)row << 6) + ((unsigned)colbytes ^ (((unsigned)row & 6u) << 3));
}

// ---------------------------------------------------------------------------
// prep: one-time W1/W2 f32 -> bf16 (96 blocks).
// ---------------------------------------------------------------------------
__global__ __launch_bounds__(256) void prep_kernel(
    const float* __restrict__ W1, const float* __restrict__ W2,
    unsigned short* __restrict__ W1b, unsigned short* __restrict__ W2b)
{
    const int bid = blockIdx.x;
    const int tid = threadIdx.x;
    if (bid < 64) {                       // W2 -> bf16 (65536 elems)
        const int i = bid * 1024 + tid * 4;
        const float4 v = *(const float4*)(W2 + i);
        ushort4 o;
        o.x = f2bf(v.x); o.y = f2bf(v.y); o.z = f2bf(v.z); o.w = f2bf(v.w);
        *(ushort4*)(W2b + i) = o;
    } else {                              // W1 -> bf16, 32-col padded rows
        const int i = (bid - 64) * 256 + tid;   // 0..8191
        const int r = i >> 5, c = i & 31;
        W1b[i] = (c < X1Dp) ? f2bf(W1[r * X1Dp + c]) : (unsigned short)0;
    }
}

// ---------------------------------------------------------------------------
// main (fused): 512 blocks x 512 threads (8 waves), 64 positions = 2 tiles.
// Producer/consumer wave-split pipeline:
//   A0(all) | {w<4:B0 || w>=4:A1p1} | {w<4:C0 || w>=4:A1p2+fin} |
//   out0 + {w>=4:B1} | C1(all) | out1
// Tile1's attention VALU overlaps tile0's MFMA/L2 phases on the same CU.
// Barrier count identical on both wave paths (wave-uniform branches).
// LDS ~30 KB, __launch_bounds__(512,4) -> VGPR<=128, 2 blocks/CU.
// ---------------------------------------------------------------------------
__global__ __launch_bounds__(512, 4) void main_kernel(
    const float* __restrict__ state, const float* __restrict__ action,
    const float* __restrict__ Wk, const float* __restrict__ Wq,
    const float* __restrict__ Wv,
    const unsigned short* __restrict__ W1b, const unsigned short* __restrict__ W2b,
    const float* __restrict__ b1, const float* __restrict__ b2,
    const float* __restrict__ Wout, const float* __restrict__ bout,
    float* __restrict__ out)
{
    const int bid   = blockIdx.x;        // 0..511
    const int batch = bid >> 1;
    const int t0    = (bid & 1) * 64;
    const int tid   = threadIdx.x;
    const int lane  = tid & 63;
    const int wave  = tid >> 6;          // 0..7
    const int quad  = lane >> 4;
    const int l16   = lane & 15;
    // A0 layout (all 512 threads): 32 t's x 16-way j-split
    const int tl0   = tid >> 4;          // 0..31
    const int jo0   = tid & 15;
    // A1 layout (waves 4-7, 256 threads): 32 t's x 8-way j-split
    const int ta1   = (tid & 255) >> 3;  // 0..31
    const int jo1   = tid & 7;

    __shared__ float4 s4[Tp];                                // 2 KB
    __shared__ float  wv[Hp * Kp * Kp];                      // 192 B
    __shared__ float  qk[64 * QKLD];                         // 4.3 KB
    __shared__ float  b1s[HIDp];                             // 1 KB
    __shared__ float  b2s[HIDp];                             // 1 KB
    __shared__ float  wouts[HIDp];                           // 1 KB
    __shared__ __align__(16) unsigned short X1s[64 * 32];    // 4 KB (swizzled)
    __shared__ __align__(16) unsigned short h1s[32 * 256];   // 16 KB (swizzled, reused per tile)
    __shared__ float partial[8][32];                         // 1 KB

    // ---- pre-issue W1b B-frags (each wave's (rt,chh) slice; used at B0 or B1) ----
    const int rtB  = wave & 1;
    const int chhB = (wave >> 1) & 1;
    bf16x8 bfr[8];
    #pragma unroll
    for (int n = 0; n < 8; ++n)
        bfr[n] = *(const bf16x8*)&W1b[(chhB * 128 + n * 16 + l16) * 32 + quad * 8];

    // ---- phase S: parallel staging + per-t precompute (64 t's) ----
    if (tid < Tp) {
        s4[tid] = ((const float4*)(state + (size_t)batch * Tp * SDp))[tid * 2];
    } else if (tid < Tp + 64) {
        const int ta = tid - Tp;            // 0..63
        const int tt = t0 + ta;
        float qs[QDp];
        {
            const float* srow = state + ((size_t)batch * Tp + tt) * SDp;
            const float4 v0 = *(const float4*)srow;
            const float4 v1 = *(const float4*)(srow + 4);
            qs[0]=v0.x; qs[1]=v0.y; qs[2]=v0.z; qs[3]=v0.w;
            qs[4]=v1.x; qs[5]=v1.y; qs[6]=v1.z; qs[7]=v1.w;
            const float* arow = action + ((size_t)batch * Tp + tt) * ADp;
            qs[8] = arow[0]; qs[9] = arow[1];
        }
        float q[Hp * Kp];
        #pragma unroll
        for (int r = 0; r < Hp * Kp; ++r) {
            float a = 0.f;
            #pragma unroll
            for (int d = 0; d < QDp; ++d) a += qs[d] * Wq[r * QDp + d];
            q[r] = a;
        }
        float* qrow = &qk[ta * QKLD];
        #pragma unroll
        for (int h = 0; h < Hp; ++h)
            #pragma unroll
            for (int c = 0; c < Kp; ++c) {
                float a = 0.f;
                #pragma unroll
                for (int k = 0; k < Kp; ++k) a += q[h * Kp + k] * Wk[(h * Kp + k) * Kp + c];
                qrow[h * 4 + c] = 0.5f * LOG2E * a;   // exp->exp2 fold; no max-shift
            }
        #pragma unroll
        for (int i = 0; i < 5; ++i) {
            const unsigned u = (unsigned)f2bf(qs[2*i]) | ((unsigned)f2bf(qs[2*i+1]) << 16);
            qrow[12 + i] = __uint_as_float(u);
        }
    } else if (tid < Tp + 64 + Hp * Kp * Kp) {
        wv[tid - Tp - 64] = Wv[tid - Tp - 64];
    }
    if (tid >= 256) {
        const int i = tid - 256;            // 0..255
        b1s[i]   = b1[i];
        b2s[i]   = b2[i];
        wouts[i] = Wout[i];
    }
    __syncthreads();                                          // bar1

    // ================= A0: tile-0 attention (all 8 waves) =================
    {
        float rq[12];
        #pragma unroll
        for (int i = 0; i < 3; ++i)
            *(float4*)&rq[i * 4] = *(const float4*)&qk[tl0 * QKLD + i * 4];
        float l[Hp] = {0.f, 0.f, 0.f};
        float ac[Hp][4] = {};
        #pragma unroll
        for (int i = 0; i < 8; ++i) {
            const int j = (jo0 << 3) | ((i + jo0) & 7);   // 2-way banks (free)
            const float4 sj = s4[j];
            #pragma unroll
            for (int h = 0; h < Hp; ++h) {
                const float d = sj.x * rq[h*4] + sj.y * rq[h*4+1]
                              + sj.z * rq[h*4+2] + sj.w * rq[h*4+3];
                const float e = __builtin_amdgcn_exp2f(d);
                l[h] += e;
                ac[h][0] += e * sj.x; ac[h][1] += e * sj.y;
                ac[h][2] += e * sj.z; ac[h][3] += e * sj.w;
            }
        }
        #pragma unroll
        for (int off = 1; off < 16; off <<= 1) {
            #pragma unroll
            for (int h = 0; h < Hp; ++h) {
                l[h] += __shfl_xor(l[h], off);
                #pragma unroll
                for (int c = 0; c < Kp; ++c) ac[h][c] += __shfl_xor(ac[h][c], off);
            }
        }
        if (jo0 == 0) {
            const float4 stt = s4[t0 + tl0];
            unsigned short rowb[32] __attribute__((aligned(16)));
            #pragma unroll
            for (int h = 0; h < Hp; ++h) {
                const float dtt = stt.x * rq[h*4] + stt.y * rq[h*4+1]
                                + stt.z * rq[h*4+2] + stt.w * rq[h*4+3];
                const float ett = __builtin_amdgcn_exp2f(dtt);
                const float inv = 1.f / (l[h] - ett);
                const float rb0 = (ac[h][0] - ett * stt.x) * inv - stt.x;
                const float rb1 = (ac[h][1] - ett * stt.y) * inv - stt.y;
                const float rb2 = (ac[h][2] - ett * stt.z) * inv - stt.z;
                const float rb3 = (ac[h][3] - ett * stt.w) * inv - stt.w;
                #pragma unroll
                for (int k = 0; k < Kp; ++k) {
                    const int r = h * Kp + k;
                    rowb[r] = f2bf(rb0 * wv[r*4] + rb1 * wv[r*4+1] + rb2 * wv[r*4+2] + rb3 * wv[r*4+3]);
                }
            }
            #pragma unroll
            for (int i = 0; i < 5; ++i) {
                const unsigned u = __float_as_uint(qk[tl0 * QKLD + 12 + i]);
                rowb[12 + 2*i] = (unsigned short)(u & 0xffffu);
                rowb[13 + 2*i] = (unsigned short)(u >> 16);
            }
            #pragma unroll
            for (int i = X1Dp; i < 32; ++i) rowb[i] = 0;
            const uint4* srcv = (const uint4*)rowb;
            #pragma unroll
            for (int i = 0; i < 4; ++i)
                *(uint4*)((char*)X1s + x1_byte(tl0, i * 16)) = srcv[i];
        }
    }
    __syncthreads();                                          // bar2

    // ============ stage 1: {w<4: B0} || {w>=4: A1 first half} ============
    float l1[Hp] = {0.f, 0.f, 0.f};
    float ac1[Hp][4] = {};
    float rq1[12];
    if (wave >= 4) {
        #pragma unroll
        for (int i = 0; i < 3; ++i)
            *(float4*)&rq1[i * 4] = *(const float4*)&qk[(32 + ta1) * QKLD + i * 4];
        #pragma unroll
        for (int i = 0; i < 8; ++i) {
            const int j = (jo1 << 4) | ((i + jo1) & 15);
            const float4 sj = s4[j];
            #pragma unroll
            for (int h = 0; h < Hp; ++h) {
                const float d = sj.x * rq1[h*4] + sj.y * rq1[h*4+1]
                              + sj.z * rq1[h*4+2] + sj.w * rq1[h*4+3];
                const float e = __builtin_amdgcn_exp2f(d);
                l1[h] += e;
                ac1[h][0] += e * sj.x; ac1[h][1] += e * sj.y;
                ac1[h][2] += e * sj.z; ac1[h][3] += e * sj.w;
            }
        }
    } else {
        // B0: tile-0 MLP1 (4 waves cover 32 rows x 256 cols)
        const bf16x8 afr = *(const bf16x8*)((const char*)X1s +
                             x1_byte(rtB * 16 + l16, quad * 16));
        #pragma unroll
        for (int n = 0; n < 8; ++n) {
            const int col = chhB * 128 + n * 16 + l16;
            f32x4 acc = {0.f, 0.f, 0.f, 0.f};
            acc = __builtin_amdgcn_mfma_f32_16x16x32_bf16(afr, bfr[n], acc, 0, 0, 0);
            const float bb = b1s[col];
            #pragma unroll
            for (int r = 0; r < 4; ++r)
                *(unsigned short*)((char*)h1s + h1_byte(rtB * 16 + quad * 4 + r, col * 2)) =
                    f2bf(fmaxf(acc[r] + bb, 0.f));
        }
    }
    __syncthreads();                                          // bar3

    // ===== stage 2: {w<4: C0} || {w>=4: A1 second half + finalize} =====
    if (wave >= 4) {
        #pragma unroll
        for (int i = 8; i < 16; ++i) {
            const int j = (jo1 << 4) | ((i + jo1) & 15);
            const float4 sj = s4[j];
            #pragma unroll
            for (int h = 0; h < Hp; ++h) {
                const float d = sj.x * rq1[h*4] + sj.y * rq1[h*4+1]
                              + sj.z * rq1[h*4+2] + sj.w * rq1[h*4+3];
                const float e = __builtin_amdgcn_exp2f(d);
                l1[h] += e;
                ac1[h][0] += e * sj.x; ac1[h][1] += e * sj.y;
                ac1[h][2] += e * sj.z; ac1[h][3] += e * sj.w;
            }
        }
        #pragma unroll
        for (int off = 1; off < 8; off <<= 1) {
            #pragma unroll
            for (int h = 0; h < Hp; ++h) {
                l1[h] += __shfl_xor(l1[h], off);
                #pragma unroll
                for (int c = 0; c < Kp; ++c) ac1[h][c] += __shfl_xor(ac1[h][c], off);
            }
        }
        if (jo1 == 0) {
            const float4 stt = s4[t0 + 32 + ta1];
            unsigned short rowb[32] __attribute__((aligned(16)));
            #pragma unroll
            for (int h = 0; h < Hp; ++h) {
                const float dtt = stt.x * rq1[h*4] + stt.y * rq1[h*4+1]
                                + stt.z * rq1[h*4+2] + stt.w * rq1[h*4+3];
                const float ett = __builtin_amdgcn_exp2f(dtt);
                const float inv = 1.f / (l1[h] - ett);
                const float rb0 = (ac1[h][0] - ett * stt.x) * inv - stt.x;
                const float rb1 = (ac1[h][1] - ett * stt.y) * inv - stt.y;
                const float rb2 = (ac1[h][2] - ett * stt.z) * inv - stt.z;
                const float rb3 = (ac1[h][3] - ett * stt.w) * inv - stt.w;
                #pragma unroll
                for (int k = 0; k < Kp; ++k) {
                    const int r = h * Kp + k;
                    rowb[r] = f2bf(rb0 * wv[r*4] + rb1 * wv[r*4+1] + rb2 * wv[r*4+2] + rb3 * wv[r*4+3]);
                }
            }
            #pragma unroll
            for (int i = 0; i < 5; ++i) {
                const unsigned u = __float_as_uint(qk[(32 + ta1) * QKLD + 12 + i]);
                rowb[12 + 2*i] = (unsigned short)(u & 0xffffu);
                rowb[13 + 2*i] = (unsigned short)(u >> 16);
            }
            #pragma unroll
            for (int i = X1Dp; i < 32; ++i) rowb[i] = 0;
            const uint4* srcv = (const uint4*)rowb;
            #pragma unroll
            for (int i = 0; i < 4; ++i)
                *(uint4*)((char*)X1s + x1_byte(32 + ta1, i * 16)) = srcv[i];
        }
    } else {
        // C0: tile-0 MLP2, wave owns 64 cols (4 groups)
        float rsum[2][4] = {};
        #pragma unroll
        for (int i = 0; i < 4; ++i) {
            const int col = wave * 64 + i * 16 + l16;
            const unsigned short* wr = W2b + (size_t)col * HIDp + quad * 8;
            bf16x8 Bf[8];
            #pragma unroll
            for (int ks = 0; ks < 8; ++ks)
                Bf[ks] = *(const bf16x8*)(wr + ks * 32);
            const float bb = b2s[col];
            const float wo = wouts[col];
            #pragma unroll
            for (int rt = 0; rt < 2; ++rt) {
                f32x4 acc = {0.f, 0.f, 0.f, 0.f};
                #pragma unroll
                for (int ks = 0; ks < 8; ++ks) {
                    const bf16x8 a8 = *(const bf16x8*)((const char*)h1s +
                                        h1_byte(rt * 16 + l16, ks * 64 + quad * 16));
                    acc = __builtin_amdgcn_mfma_f32_16x16x32_bf16(a8, Bf[ks], acc, 0, 0, 0);
                }
                #pragma unroll
                for (int r = 0; r < 4; ++r)
                    rsum[rt][r] += fmaxf(acc[r] + bb, 0.f) * wo;
            }
        }
        #pragma unroll
        for (int off = 1; off < 16; off <<= 1)
            #pragma unroll
            for (int rt = 0; rt < 2; ++rt)
                #pragma unroll
                for (int r = 0; r < 4; ++r)
                    rsum[rt][r] += __shfl_xor(rsum[rt][r], off);
        if (l16 == 0)
            #pragma unroll
            for (int rt = 0; rt < 2; ++rt)
                #pragma unroll
                for (int r = 0; r < 4; ++r)
                    partial[wave][rt * 16 + quad * 4 + r] = rsum[rt][r];
    }
    __syncthreads();                                          // bar4

    // ---- out0 (tile-0 partials complete) + {w>=4: B1} ----
    if (tid < 32) {
        out[(size_t)batch * Tp + t0 + tid] =
            partial[0][tid] + partial[1][tid] + partial[2][tid]
          + partial[3][tid] + bout[0];
    }
    if (wave >= 4) {
        // B1: tile-1 MLP1 (4 waves cover rows 32-63 -> h1s rows 0-31, reused)
        const bf16x8 afr = *(const bf16x8*)((const char*)X1s +
                             x1_byte(32 + rtB * 16 + l16, quad * 16));
        #pragma unroll
        for (int n = 0; n < 8; ++n) {
            const int col = chhB * 128 + n * 16 + l16;
            f32x4 acc = {0.f, 0.f, 0.f, 0.f};
            acc = __builtin_amdgcn_mfma_f32_16x16x32_bf16(afr, bfr[n], acc, 0, 0, 0);
            const float bb = b1s[col];
            #pragma unroll
            for (int r = 0; r < 4; ++r)
                *(unsigned short*)((char*)h1s + h1_byte(rtB * 16 + quad * 4 + r, col * 2)) =
                    f2bf(fmaxf(acc[r] + bb, 0.f));
        }
    }
    __syncthreads();                                          // bar5

    // ================= C1: tile-1 MLP2 (ALL 8 waves, 32 cols each) =================
    {
        float rsum[2][4] = {};
        #pragma unroll
        for (int i = 0; i < 2; ++i) {
            const int col = wave * 32 + i * 16 + l16;
            const unsigned short* wr = W2b + (size_t)col * HIDp + quad * 8;
            bf16x8 Bf[8];
            #pragma unroll
            for (int ks = 0; ks < 8; ++ks)
                Bf[ks] = *(const bf16x8*)(wr + ks * 32);
            const float bb = b2s[col];
            const float wo = wouts[col];
            #pragma unroll
            for (int rt = 0; rt < 2; ++rt) {
                f32x4 acc = {0.f, 0.f, 0.f, 0.f};
                #pragma unroll
                for (int ks = 0; ks < 8; ++ks) {
                    const bf16x8 a8 = *(const bf16x8*)((const char*)h1s +
                                        h1_byte(rt * 16 + l16, ks * 64 + quad * 16));
                    acc = __builtin_amdgcn_mfma_f32_16x16x32_bf16(a8, Bf[ks], acc, 0, 0, 0);
                }
                #pragma unroll
                for (int r = 0; r < 4; ++r)
                    rsum[rt][r] += fmaxf(acc[r] + bb, 0.f) * wo;
            }
        }
        #pragma unroll
        for (int off = 1; off < 16; off <<= 1)
            #pragma unroll
            for (int rt = 0; rt < 2; ++rt)
                #pragma unroll
                for (int r = 0; r < 4; ++r)
                    rsum[rt][r] += __shfl_xor(rsum[rt][r], off);
        if (l16 == 0)
            #pragma unroll
            for (int rt = 0; rt < 2; ++rt)
                #pragma unroll
                for (int r = 0; r < 4; ++r)
                    partial[wave][rt * 16 + quad * 4 + r] = rsum[rt][r];
    }
    __syncthreads();                                          // bar6

    if (tid < 32) {
        float o = bout[0];
        #pragma unroll
        for (int w = 0; w < 8; ++w) o += partial[w][tid];
        out[(size_t)batch * Tp + t0 + 32 + tid] = o;
    }
}

extern "C" void kernel_launch(void* const* d_in, const int* in_sizes, int n_in,
                              void* d_out, int out_size, void* d_ws, size_t ws_size,
                              hipStream_t stream) {
    const float* state  = (const float*)d_in[0];
    const float* action = (const float*)d_in[1];
    const float* Wk     = (const float*)d_in[2];
    const float* Wq     = (const float*)d_in[3];
    const float* Wv     = (const float*)d_in[4];
    const float* W1     = (const float*)d_in[5];
    const float* b1     = (const float*)d_in[6];
    const float* W2     = (const float*)d_in[7];
    const float* b2     = (const float*)d_in[8];
    const float* Wout   = (const float*)d_in[9];
    const float* bout   = (const float*)d_in[10];
    float* out = (float*)d_out;

    char* ws = (char*)d_ws;
    unsigned short* W1b = (unsigned short*)(ws);           // 16 KB
    unsigned short* W2b = (unsigned short*)(ws + 16384);   // 128 KB

    prep_kernel<<<96, 256, 0, stream>>>(W1, W2, W1b, W2b);
    main_kernel<<<2 * Bp, 512, 0, stream>>>(state, action, Wk, Wq, Wv,
                                            W1b, W2b, b1, b2, Wout, bout, out);
}

// Round 11
// 108.517 us; speedup vs baseline: 1.0201x; 1.0201x over previous
//
#include <hip/hip_runtime.h>
#include <math.h>

#define Bp 256
#define Tp 128
#define SDp 8
#define ADp 2
#define Hp 3
#define Kp 4
#define HIDp 256
#define QDp (SDp + ADp)       // 10
#define X1Dp (Hp * Kp + QDp)  // 22  (row padded to 32 bf16 = 64 B)
#define QKLD 17               // qk row stride (floats)
#define LOG2E 1.4426950408889634f

typedef short bf16x8 __attribute__((ext_vector_type(8)));
typedef float f32x4  __attribute__((ext_vector_type(4)));

__device__ __forceinline__ unsigned short f2bf(float f) {
    unsigned u = __float_as_uint(f);
    unsigned r = (u + 0x7FFFu + ((u >> 16) & 1u)) >> 16;
    return (unsigned short)r;
}

// packed f32x2 -> bf16x2 (RNE), gfx950 has the instruction but no builtin
__device__ __forceinline__ unsigned cvtpk(float lo, float hi) {
    unsigned r;
    asm("v_cvt_pk_bf16_f32 %0, %1, %2" : "=v"(r) : "v"(lo), "v"(hi));
    return r;
}

// h1 LDS: row stride 512 B, XOR bits 4-6 with row&7 -> conflict-free b128 col reads
__device__ __forceinline__ unsigned h1_byte(int row, int colbytes) {
    return (((unsigned)row << 9) + (unsigned)colbytes) ^ ((unsigned)(row & 7) << 4);
}
// 64B-row LDS tiles (X1s, W1s): XOR bytes 4-5 with row bits 1-2 -> conflict-free b128
__device__ __forceinline__ unsigned x1_byte(int row, int colbytes) {
    return ((unsigned)row << 6) + ((unsigned)colbytes ^ (((unsigned)row & 6u) << 3));
}

// ---------------------------------------------------------------------------
// Single fused kernel (R6 structure; prep folded in — ONE launch, no ws):
//  - phase S: s4 || qkp precompute || wv staging, PLUS per-block W1 f32->bf16
//    into swizzled LDS W1s (22.5 KB read, trivial; removes prep dependency).
//  - phase A: 16-iter j-loop (jo 8-way), no max-shift, j==t post-subtracted;
//    shfl_xor(1,2,4) combine; X1 row -> swizzled LDS.
//  - phase B: MLP1; B-frags from W1s (LDS, conflict-free); h1 -> swizzled LDS.
//  - phase C: MLP2; W2 read as f32 from L2 and converted on the fly with
//    v_cvt_pk_bf16_f32 (R9 proved W2 byte volume is not the bottleneck);
//    8 half-steps with depth-1 prefetch; relu+Wout in-register; shfl reduce.
// LDS ~39.7 KB -> 4 blocks/CU (16 waves/CU), same occupancy as R6.
// b1/b2/Wout read from global (L1-resident) to stay under the LDS budget.
// ---------------------------------------------------------------------------
__global__ __launch_bounds__(256, 4) void main_kernel(
    const float* __restrict__ state, const float* __restrict__ action,
    const float* __restrict__ Wk, const float* __restrict__ Wq,
    const float* __restrict__ Wv, const float* __restrict__ W1,
    const float* __restrict__ b1, const float* __restrict__ W2,
    const float* __restrict__ b2, const float* __restrict__ Wout,
    const float* __restrict__ bout, float* __restrict__ out)
{
    const int bid   = blockIdx.x;
    const int batch = bid >> 2;
    const int t0    = (bid & 3) * 32;
    const int tid   = threadIdx.x;
    const int lane  = tid & 63;
    const int wave  = tid >> 6;     // 0..3
    const int quad  = lane >> 4;
    const int l16   = lane & 15;
    const int t_loc = tid >> 3;     // 0..31
    const int jo    = tid & 7;      // 8-way j split
    const int t     = t0 + t_loc;

    __shared__ float4 s4[Tp];                                // 2 KB
    __shared__ float  wv[Hp * Kp * Kp];                      // 192 B
    __shared__ float  qk[32 * QKLD];                         // 2.1 KB
    __shared__ __align__(16) unsigned short X1s[32 * 32];    // 2 KB (swizzled)
    __shared__ __align__(16) unsigned short W1s[256 * 32];   // 16 KB (swizzled)
    __shared__ __align__(16) unsigned short h1s[32 * 256];   // 16 KB (swizzled)
    __shared__ float partial[4][32];                         // 512 B

    // ---- phase S: parallel staging + per-t precompute + W1 -> LDS ----
    if (tid < Tp) {
        s4[tid] = ((const float4*)(state + (size_t)batch * Tp * SDp))[tid * 2];
    } else if (tid < 160) {
        const int ta = tid - 128;           // 0..31
        const int tt = t0 + ta;
        float qs[QDp];
        {
            const float* srow = state + ((size_t)batch * Tp + tt) * SDp;
            const float4 v0 = *(const float4*)srow;
            const float4 v1 = *(const float4*)(srow + 4);
            qs[0]=v0.x; qs[1]=v0.y; qs[2]=v0.z; qs[3]=v0.w;
            qs[4]=v1.x; qs[5]=v1.y; qs[6]=v1.z; qs[7]=v1.w;
            const float* arow = action + ((size_t)batch * Tp + tt) * ADp;
            qs[8] = arow[0]; qs[9] = arow[1];
        }
        float q[Hp * Kp];
        #pragma unroll
        for (int r = 0; r < Hp * Kp; ++r) {
            float a = 0.f;
            #pragma unroll
            for (int d = 0; d < QDp; ++d) a += qs[d] * Wq[r * QDp + d];
            q[r] = a;
        }
        float* qrow = &qk[ta * QKLD];
        #pragma unroll
        for (int h = 0; h < Hp; ++h)
            #pragma unroll
            for (int c = 0; c < Kp; ++c) {
                float a = 0.f;
                #pragma unroll
                for (int k = 0; k < Kp; ++k) a += q[h * Kp + k] * Wk[(h * Kp + k) * Kp + c];
                qrow[h * 4 + c] = 0.5f * LOG2E * a;   // exp->exp2 fold; no max-shift
            }
        #pragma unroll
        for (int i = 0; i < 5; ++i)
            qrow[12 + i] = __uint_as_float(cvtpk(qs[2*i], qs[2*i+1]));
    } else if (tid < 160 + Hp * Kp * Kp) {
        wv[tid - 160] = Wv[tid - 160];
    }
    // W1 row tid -> bf16, zero-padded to 32 cols, swizzled LDS (all 256 threads)
    {
        const float* wr = W1 + tid * X1Dp;   // 22 floats, 8B-aligned
        float w[22];
        #pragma unroll
        for (int i = 0; i < 11; ++i) {
            const float2 v = *(const float2*)(wr + i * 2);
            w[2*i] = v.x; w[2*i+1] = v.y;
        }
        unsigned rb[16];
        #pragma unroll
        for (int i = 0; i < 11; ++i) rb[i] = cvtpk(w[2*i], w[2*i+1]);
        #pragma unroll
        for (int i = 11; i < 16; ++i) rb[i] = 0u;
        const uint4* sv = (const uint4*)rb;
        #pragma unroll
        for (int i = 0; i < 4; ++i)
            *(uint4*)((char*)W1s + x1_byte(tid, i * 16)) = sv[i];
    }
    __syncthreads();

    // ---- phase A: j-loop (all 256 threads; 16 j's each) ----
    float rq[12];
    #pragma unroll
    for (int i = 0; i < 3; ++i)
        *(float4*)&rq[i * 4] = *(const float4*)&qk[t_loc * QKLD + i * 4];

    float l[Hp] = {0.f, 0.f, 0.f};
    float ac[Hp][4] = {};
    #pragma unroll
    for (int i = 0; i < 16; ++i) {
        const int j = (jo << 4) | ((i + jo) & 15);   // rotated: conflict-free banks
        const float4 sj = s4[j];
        #pragma unroll
        for (int h = 0; h < Hp; ++h) {
            const float d = sj.x * rq[h*4] + sj.y * rq[h*4+1]
                          + sj.z * rq[h*4+2] + sj.w * rq[h*4+3];
            const float e = __builtin_amdgcn_exp2f(d);   // no j==t branch
            l[h] += e;
            ac[h][0] += e * sj.x; ac[h][1] += e * sj.y;
            ac[h][2] += e * sj.z; ac[h][3] += e * sj.w;
        }
    }
    #pragma unroll
    for (int off = 1; off < 8; off <<= 1) {
        #pragma unroll
        for (int h = 0; h < Hp; ++h) {
            l[h] += __shfl_xor(l[h], off);
            #pragma unroll
            for (int c = 0; c < Kp; ++c) ac[h][c] += __shfl_xor(ac[h][c], off);
        }
    }

    if (jo == 0) {
        const float4 st = s4[t];
        unsigned short rowb[32] __attribute__((aligned(16)));
        #pragma unroll
        for (int h = 0; h < Hp; ++h) {
            // remove the j==t term: e_tt = exp2(dot(qkp_h, s_t))
            const float dtt = st.x * rq[h*4] + st.y * rq[h*4+1]
                            + st.z * rq[h*4+2] + st.w * rq[h*4+3];
            const float ett = __builtin_amdgcn_exp2f(dtt);
            const float inv = 1.f / (l[h] - ett);
            const float rb0 = (ac[h][0] - ett * st.x) * inv - st.x;
            const float rb1 = (ac[h][1] - ett * st.y) * inv - st.y;
            const float rb2 = (ac[h][2] - ett * st.z) * inv - st.z;
            const float rb3 = (ac[h][3] - ett * st.w) * inv - st.w;
            #pragma unroll
            for (int k = 0; k < Kp; ++k) {
                const int r = h * Kp + k;
                rowb[r] = f2bf(rb0 * wv[r*4] + rb1 * wv[r*4+1] + rb2 * wv[r*4+2] + rb3 * wv[r*4+3]);
            }
        }
        #pragma unroll
        for (int i = 0; i < 5; ++i) {
            const unsigned u = __float_as_uint(qk[t_loc * QKLD + 12 + i]);
            rowb[12 + 2*i] = (unsigned short)(u & 0xffffu);
            rowb[13 + 2*i] = (unsigned short)(u >> 16);
        }
        #pragma unroll
        for (int i = X1Dp; i < 32; ++i) rowb[i] = 0;

        const uint4* srcv = (const uint4*)rowb;
        #pragma unroll
        for (int i = 0; i < 4; ++i)
            *(uint4*)((char*)X1s + x1_byte(t_loc, i * 16)) = srcv[i];
    }
    __syncthreads();

    // ---- phase B: MLP1 (wave -> row-tile rt, col-half chh); B-frags from W1s ----
    {
        const int rt  = wave & 1;
        const int chh = wave >> 1;
        bf16x8 bfr[8];
        #pragma unroll
        for (int n = 0; n < 8; ++n)
            bfr[n] = *(const bf16x8*)((const char*)W1s +
                       x1_byte(chh * 128 + n * 16 + l16, quad * 16));
        const bf16x8 afr = *(const bf16x8*)((const char*)X1s +
                             x1_byte(rt * 16 + l16, quad * 16));
        #pragma unroll
        for (int n = 0; n < 8; ++n) {
            const int col = chh * 128 + n * 16 + l16;
            f32x4 acc = {0.f, 0.f, 0.f, 0.f};
            acc = __builtin_amdgcn_mfma_f32_16x16x32_bf16(afr, bfr[n], acc, 0, 0, 0);
            const float bb = b1[col];
            #pragma unroll
            for (int r = 0; r < 4; ++r) {
                const int row = rt * 16 + quad * 4 + r;
                *(unsigned short*)((char*)h1s + h1_byte(row, col * 2)) =
                    f2bf(fmaxf(acc[r] + bb, 0.f));
            }
        }
    }
    __syncthreads();

    // ---- phase C: MLP2 + out; W2 f32 on-the-fly cvt, 8 half-steps,
    //      depth-1 prefetch (wave owns cols [wave*64, wave*64+64)) ----
    float rsum[2][4] = {};
    f32x4 acc0 = {0.f, 0.f, 0.f, 0.f};
    f32x4 acc1 = {0.f, 0.f, 0.f, 0.f};
    float4 sg[8];
    {   // stage for step 0 (group 0, half 0)
        const float* wp = W2 + (size_t)(wave * 64 + l16) * HIDp + quad * 8;
        #pragma unroll
        for (int m = 0; m < 4; ++m) {
            sg[2*m]   = *(const float4*)(wp + m * 32);
            sg[2*m+1] = *(const float4*)(wp + m * 32 + 4);
        }
    }
    #pragma unroll
    for (int k = 0; k < 8; ++k) {
        const int i  = k >> 1;
        const int hf = k & 1;
        float4 nx[8];
        if (k < 7) {   // prefetch next half-step (in flight under cvt+MFMA below)
            const int ni  = (k + 1) >> 1;
            const int nhf = (k + 1) & 1;
            const float* wp = W2 + (size_t)((wave * 4 + ni) * 16 + l16) * HIDp
                            + nhf * 128 + quad * 8;
            #pragma unroll
            for (int m = 0; m < 4; ++m) {
                nx[2*m]   = *(const float4*)(wp + m * 32);
                nx[2*m+1] = *(const float4*)(wp + m * 32 + 4);
            }
        }
        #pragma unroll
        for (int m = 0; m < 4; ++m) {
            union { unsigned u[4]; bf16x8 v; } cv;
            cv.u[0] = cvtpk(sg[2*m].x,   sg[2*m].y);
            cv.u[1] = cvtpk(sg[2*m].z,   sg[2*m].w);
            cv.u[2] = cvtpk(sg[2*m+1].x, sg[2*m+1].y);
            cv.u[3] = cvtpk(sg[2*m+1].z, sg[2*m+1].w);
            const int ks = hf * 4 + m;
            const bf16x8 a0 = *(const bf16x8*)((const char*)h1s +
                                h1_byte(l16,      ks * 64 + quad * 16));
            const bf16x8 a1 = *(const bf16x8*)((const char*)h1s +
                                h1_byte(16 + l16, ks * 64 + quad * 16));
            acc0 = __builtin_amdgcn_mfma_f32_16x16x32_bf16(a0, cv.v, acc0, 0, 0, 0);
            acc1 = __builtin_amdgcn_mfma_f32_16x16x32_bf16(a1, cv.v, acc1, 0, 0, 0);
        }
        if (hf == 1) {   // finalize column-group i
            const int col = (wave * 4 + i) * 16 + l16;
            const float bb = b2[col];
            const float wo = Wout[col];
            #pragma unroll
            for (int r = 0; r < 4; ++r) {
                rsum[0][r] += fmaxf(acc0[r] + bb, 0.f) * wo;
                rsum[1][r] += fmaxf(acc1[r] + bb, 0.f) * wo;
            }
            acc0 = (f32x4){0.f, 0.f, 0.f, 0.f};
            acc1 = (f32x4){0.f, 0.f, 0.f, 0.f};
        }
        #pragma unroll
        for (int m = 0; m < 8; ++m) sg[m] = nx[m];   // SSA-renamed
    }

    #pragma unroll
    for (int off = 1; off < 16; off <<= 1)
        #pragma unroll
        for (int rt = 0; rt < 2; ++rt)
            #pragma unroll
            for (int r = 0; r < 4; ++r)
                rsum[rt][r] += __shfl_xor(rsum[rt][r], off);

    if (l16 == 0) {
        #pragma unroll
        for (int rt = 0; rt < 2; ++rt)
            #pragma unroll
            for (int r = 0; r < 4; ++r)
                partial[wave][rt * 16 + quad * 4 + r] = rsum[rt][r];
    }
    __syncthreads();

    if (tid < 32) {
        out[(size_t)batch * Tp + t0 + tid] =
            partial[0][tid] + partial[1][tid] + partial[2][tid]
          + partial[3][tid] + bout[0];
    }
}

extern "C" void kernel_launch(void* const* d_in, const int* in_sizes, int n_in,
                              void* d_out, int out_size, void* d_ws, size_t ws_size,
                              hipStream_t stream) {
    const float* state  = (const float*)d_in[0];
    const float* action = (const float*)d_in[1];
    const float* Wk     = (const float*)d_in[2];
    const float* Wq     = (const float*)d_in[3];
    const float* Wv     = (const float*)d_in[4];
    const float* W1     = (const float*)d_in[5];
    const float* b1     = (const float*)d_in[6];
    const float* W2     = (const float*)d_in[7];
    const float* b2     = (const float*)d_in[8];
    const float* Wout   = (const float*)d_in[9];
    const float* bout   = (const float*)d_in[10];
    float* out = (float*)d_out;

    (void)d_ws; (void)ws_size;   // no workspace: single launch, no prep pass

    main_kernel<<<4 * Bp, 256, 0, stream>>>(state, action, Wk, Wq, Wv,
                                            W1, b1, W2, b2, Wout, bout, out);
}

// Round 12
// 102.590 us; speedup vs baseline: 1.0790x; 1.0578x over previous
//
#include <hip/hip_runtime.h>
#include <math.h>

#define Bp 256
#define Tp 128
#define SDp 8
#define ADp 2
#define Hp 3
#define Kp 4
#define HIDp 256
#define QDp (SDp + ADp)       // 10
#define X1Dp (Hp * Kp + QDp)  // 22  (row padded to 32 bf16 = 64 B)
#define LOG2E 1.4426950408889634f

typedef short bf16x8 __attribute__((ext_vector_type(8)));
typedef float f32x4  __attribute__((ext_vector_type(4)));

__device__ __forceinline__ unsigned short f2bf(float f) {
    unsigned u = __float_as_uint(f);
    unsigned r = (u + 0x7FFFu + ((u >> 16) & 1u)) >> 16;
    return (unsigned short)r;
}
__device__ __forceinline__ unsigned cvtpk(float lo, float hi) {
    unsigned r;
    asm("v_cvt_pk_bf16_f32 %0, %1, %2" : "=v"(r) : "v"(lo), "v"(hi));
    return r;
}

// h1 LDS: row stride 512 B, XOR bits 4-6 with row&7 -> conflict-free b128 col reads
__device__ __forceinline__ unsigned h1_byte(int row, int colbytes) {
    return (((unsigned)row << 9) + (unsigned)colbytes) ^ ((unsigned)(row & 7) << 4);
}
// 64B-row tiles (X1s): XOR bytes 4-5 with row bits 1-2
__device__ __forceinline__ unsigned x1_byte(int row, int colbytes) {
    return ((unsigned)row << 6) + ((unsigned)colbytes ^ (((unsigned)row & 6u) << 3));
}
// 256B-row tiles (E, S1eT): XOR byte bits 4-7 with row&15 -> <=2-way on b128
__device__ __forceinline__ unsigned e_byte(int row, int colbytes) {
    return ((unsigned)row << 8) + ((unsigned)colbytes ^ (((unsigned)row & 15u) << 4));
}

// ---------------------------------------------------------------------------
// prep: one-time W1/W2 f32 -> bf16 (96 blocks). (R6 verbatim)
// ---------------------------------------------------------------------------
__global__ __launch_bounds__(256) void prep_kernel(
    const float* __restrict__ W1, const float* __restrict__ W2,
    unsigned short* __restrict__ W1b, unsigned short* __restrict__ W2b)
{
    const int bid = blockIdx.x;
    const int tid = threadIdx.x;
    if (bid < 64) {
        const int i = bid * 1024 + tid * 4;
        const float4 v = *(const float4*)(W2 + i);
        ushort4 o;
        o.x = f2bf(v.x); o.y = f2bf(v.y); o.z = f2bf(v.z); o.w = f2bf(v.w);
        *(ushort4*)(W2b + i) = o;
    } else {
        const int i = (bid - 64) * 256 + tid;   // 0..8191
        const int r = i >> 5, c = i & 31;
        W1b[i] = (c < X1Dp) ? f2bf(W1[r * X1Dp + c]) : (unsigned short)0;
    }
}

// ---------------------------------------------------------------------------
// main: 1024 blocks x 256 threads, 32 positions/block. Phase A is now MFMA:
//   mm1: D[96(=3h x 32t), 128j] = QKP[96,4pad32] @ S^T[4,128]  (48 MFMA)
//   exp2 each D elem -> E bf16 (LDS, XOR-swizzled)
//   mm2: AC[96, 5pad16] = E[96,128] @ [S|1][128,5]              (24 MFMA)
// e_tt (j==t) read back from E and subtracted at finalize.
// Phases B/C = R6 verbatim (W1b/W2b bf16 from workspace; b1/b2/Wout global).
// LDS 40.1 KB -> 4 blocks/CU. E region aliased by X1s+h1s after mm2.
// ---------------------------------------------------------------------------
__global__ __launch_bounds__(256, 4) void main_kernel(
    const float* __restrict__ state, const float* __restrict__ action,
    const float* __restrict__ Wk, const float* __restrict__ Wq,
    const float* __restrict__ Wv,
    const unsigned short* __restrict__ W1b, const unsigned short* __restrict__ W2b,
    const float* __restrict__ b1, const float* __restrict__ b2,
    const float* __restrict__ Wout, const float* __restrict__ bout,
    float* __restrict__ out)
{
    const int bid   = blockIdx.x;
    const int batch = bid >> 2;
    const int t0    = (bid & 3) * 32;
    const int tid   = threadIdx.x;
    const int lane  = tid & 63;
    const int wave  = tid >> 6;     // 0..3
    const int quad  = lane >> 4;
    const int l16   = lane & 15;

    __shared__ float4 s4[Tp];                                 // 2048 B
    __shared__ float  wv[Hp * Kp * Kp];                       // 192 B
    __shared__ float  qkpc[96 * 4];                           // 1536 B (f32 qkp rows)
    __shared__ unsigned qsb[32 * 5];                          // 640 B (packed bf16 qs)
    __shared__ __align__(16) unsigned short S1eT[16 * 128];   // 4096 B ([c][j], e_byte swz)
    __shared__ __align__(16) char REG[24576];                 // E[96][128]bf16; later X1s+h1s
    __shared__ float D2L[96 * 17];                            // 6528 B
    __shared__ float partial[4][32];                          // 512 B

    unsigned short* E   = (unsigned short*)REG;
    unsigned short* X1s = (unsigned short*)REG;               // after mm2
    unsigned short* h1s = (unsigned short*)(REG + 2048);      // after finalize

    const bf16x8 zfrag = {0, 0, 0, 0, 0, 0, 0, 0};

    // ---- phase S ----
    if (tid < Tp) {
        const float4 v = ((const float4*)(state + (size_t)batch * Tp * SDp))[tid * 2];
        s4[tid] = v;
        // S1eT rows 0-3, col j=tid
        *(unsigned short*)((char*)S1eT + e_byte(0, tid * 2)) = f2bf(v.x);
        *(unsigned short*)((char*)S1eT + e_byte(1, tid * 2)) = f2bf(v.y);
        *(unsigned short*)((char*)S1eT + e_byte(2, tid * 2)) = f2bf(v.z);
        *(unsigned short*)((char*)S1eT + e_byte(3, tid * 2)) = f2bf(v.w);
    } else if (tid < 160) {
        const int ta = tid - 128;           // 0..31
        const int tt = t0 + ta;
        float qs[QDp];
        {
            const float* srow = state + ((size_t)batch * Tp + tt) * SDp;
            const float4 v0 = *(const float4*)srow;
            const float4 v1 = *(const float4*)(srow + 4);
            qs[0]=v0.x; qs[1]=v0.y; qs[2]=v0.z; qs[3]=v0.w;
            qs[4]=v1.x; qs[5]=v1.y; qs[6]=v1.z; qs[7]=v1.w;
            const float* arow = action + ((size_t)batch * Tp + tt) * ADp;
            qs[8] = arow[0]; qs[9] = arow[1];
        }
        float q[Hp * Kp];
        #pragma unroll
        for (int r = 0; r < Hp * Kp; ++r) {
            float a = 0.f;
            #pragma unroll
            for (int d = 0; d < QDp; ++d) a += qs[d] * Wq[r * QDp + d];
            q[r] = a;
        }
        #pragma unroll
        for (int h = 0; h < Hp; ++h) {
            float4 p;
            #pragma unroll
            for (int c = 0; c < Kp; ++c) {
                float a = 0.f;
                #pragma unroll
                for (int k = 0; k < Kp; ++k) a += q[h * Kp + k] * Wk[(h * Kp + k) * Kp + c];
                p[c] = 0.5f * LOG2E * a;     // exp -> exp2 fold; no max-shift
            }
            *(float4*)&qkpc[(h * 32 + ta) * 4] = p;
        }
        #pragma unroll
        for (int i = 0; i < 5; ++i)
            qsb[ta * 5 + i] = cvtpk(qs[2*i], qs[2*i+1]);
    } else {
        const int i = tid - 160;            // 0..95
        const unsigned ones = 0x3F803F80u;  // bf16(1.0) pair
        #pragma unroll
        for (int rep = 0; rep < 2; ++rep) {
            const int v = i + rep * 96;
            if (v < 192) {                  // S1eT rows 4..15 (row4 = ones)
                const int row = 4 + (v >> 4);
                const int cb  = (v & 15) * 16;
                const unsigned fill = (row == 4) ? ones : 0u;
                uint4 z; z.x = fill; z.y = fill; z.z = fill; z.w = fill;
                *(uint4*)((char*)S1eT + e_byte(row, cb)) = z;
            }
        }
        if (i < Hp * Kp * Kp) wv[i] = Wv[i];
    }
    __syncthreads();

    // ---- mm1: scores + exp2 -> E ----
    {
        bf16x8 Am[6];
        #pragma unroll
        for (int m = 0; m < 6; ++m) {
            union { unsigned u[4]; bf16x8 v; } a;
            const float4 p = *(const float4*)&qkpc[(m * 16 + l16) * 4];
            a.u[0] = cvtpk(p.x, p.y); a.u[1] = cvtpk(p.z, p.w);
            a.u[2] = 0u; a.u[3] = 0u;
            Am[m] = (quad == 0) ? a.v : zfrag;
        }
        #pragma unroll
        for (int nn = 0; nn < 2; ++nn) {
            const int n = wave * 2 + nn;
            union { unsigned u[4]; bf16x8 v; } b;
            const float4 sv = s4[n * 16 + l16];
            b.u[0] = cvtpk(sv.x, sv.y); b.u[1] = cvtpk(sv.z, sv.w);
            b.u[2] = 0u; b.u[3] = 0u;
            const bf16x8 Bf = (quad == 0) ? b.v : zfrag;
            #pragma unroll
            for (int m = 0; m < 6; ++m) {
                f32x4 d = {0.f, 0.f, 0.f, 0.f};
                d = __builtin_amdgcn_mfma_f32_16x16x32_bf16(Am[m], Bf, d, 0, 0, 0);
                #pragma unroll
                for (int r = 0; r < 4; ++r) {
                    const int row = m * 16 + quad * 4 + r;
                    const int col = n * 16 + l16;
                    *(unsigned short*)((char*)E + e_byte(row, col * 2)) =
                        f2bf(__builtin_amdgcn_exp2f(d[r]));
                }
            }
        }
    }
    __syncthreads();

    // ---- e_tt pre-read (E complete; X1s will alias E after next barrier) ----
    float ett[3] = {0.f, 0.f, 0.f};
    if (tid < 32) {
        #pragma unroll
        for (int h = 0; h < Hp; ++h) {
            const unsigned short ev = *(const unsigned short*)
                ((const char*)E + e_byte(h * 32 + tid, (t0 + tid) * 2));
            ett[h] = __uint_as_float(((unsigned)ev) << 16);
        }
    }

    // ---- mm2: AC / l sums -> D2L ----
    {
        const int nm = (wave < 2) ? 2 : 1;
        for (int mi = 0; mi < nm; ++mi) {
            const int m = (mi == 0) ? wave : (4 + wave);
            f32x4 acc = {0.f, 0.f, 0.f, 0.f};
            #pragma unroll
            for (int ks = 0; ks < 4; ++ks) {
                const bf16x8 a = *(const bf16x8*)((const char*)E +
                                    e_byte(m * 16 + l16, ks * 64 + quad * 16));
                const bf16x8 b = *(const bf16x8*)((const char*)S1eT +
                                    e_byte(l16, ks * 64 + quad * 16));
                acc = __builtin_amdgcn_mfma_f32_16x16x32_bf16(a, b, acc, 0, 0, 0);
            }
            #pragma unroll
            for (int r = 0; r < 4; ++r)
                D2L[(m * 16 + quad * 4 + r) * 17 + l16] = acc[r];
        }
    }
    __syncthreads();

    // ---- finalize: x rows -> X1s (aliases E; safe after barrier) ----
    if (tid < 32) {
        const float4 st = s4[t0 + tid];
        const float stc[4] = {st.x, st.y, st.z, st.w};
        unsigned short rowb[32] __attribute__((aligned(16)));
        #pragma unroll
        for (int h = 0; h < Hp; ++h) {
            const int th = h * 32 + tid;
            const float lsum = D2L[th * 17 + 4] - ett[h];
            const float inv  = 1.f / lsum;
            float rb[4];
            #pragma unroll
            for (int c = 0; c < 4; ++c)
                rb[c] = (D2L[th * 17 + c] - ett[h] * stc[c]) * inv - stc[c];
            #pragma unroll
            for (int k = 0; k < Kp; ++k) {
                const int r = h * Kp + k;
                rowb[r] = f2bf(rb[0]*wv[r*4] + rb[1]*wv[r*4+1] + rb[2]*wv[r*4+2] + rb[3]*wv[r*4+3]);
            }
        }
        #pragma unroll
        for (int i = 0; i < 5; ++i) {
            const unsigned u = qsb[tid * 5 + i];
            rowb[12 + 2*i] = (unsigned short)(u & 0xffffu);
            rowb[13 + 2*i] = (unsigned short)(u >> 16);
        }
        #pragma unroll
        for (int i = X1Dp; i < 32; ++i) rowb[i] = 0;
        const uint4* srcv = (const uint4*)rowb;
        #pragma unroll
        for (int i = 0; i < 4; ++i)
            *(uint4*)((char*)X1s + x1_byte(tid, i * 16)) = srcv[i];
    }
    __syncthreads();

    // ---- phase B: MLP1 (R6) ----
    {
        const int rt  = wave & 1;
        const int chh = wave >> 1;
        bf16x8 bfr[8];
        #pragma unroll
        for (int n = 0; n < 8; ++n)
            bfr[n] = *(const bf16x8*)&W1b[(chh * 128 + n * 16 + l16) * 32 + quad * 8];
        const bf16x8 afr = *(const bf16x8*)((const char*)X1s +
                             x1_byte(rt * 16 + l16, quad * 16));
        #pragma unroll
        for (int n = 0; n < 8; ++n) {
            const int col = chh * 128 + n * 16 + l16;
            f32x4 acc = {0.f, 0.f, 0.f, 0.f};
            acc = __builtin_amdgcn_mfma_f32_16x16x32_bf16(afr, bfr[n], acc, 0, 0, 0);
            const float bb = b1[col];
            #pragma unroll
            for (int r = 0; r < 4; ++r) {
                const int row = rt * 16 + quad * 4 + r;
                *(unsigned short*)((char*)h1s + h1_byte(row, col * 2)) =
                    f2bf(fmaxf(acc[r] + bb, 0.f));
            }
        }
    }
    __syncthreads();

    // ---- phase C: MLP2 + out (R6) ----
    float rsum[2][4] = {};
    #pragma unroll
    for (int i = 0; i < 4; ++i) {
        const int col = (wave * 4 + i) * 16 + l16;
        const unsigned short* wr = W2b + (size_t)col * HIDp + quad * 8;
        bf16x8 Bf[8];
        #pragma unroll
        for (int ks = 0; ks < 8; ++ks)
            Bf[ks] = *(const bf16x8*)(wr + ks * 32);
        const float bb = b2[col];
        const float wo = Wout[col];
        #pragma unroll
        for (int rt = 0; rt < 2; ++rt) {
            bf16x8 A8[8];
            #pragma unroll
            for (int ks = 0; ks < 8; ++ks)
                A8[ks] = *(const bf16x8*)((const char*)h1s +
                           h1_byte(rt * 16 + l16, ks * 64 + quad * 16));
            f32x4 acc = {0.f, 0.f, 0.f, 0.f};
            #pragma unroll
            for (int ks = 0; ks < 8; ++ks)
                acc = __builtin_amdgcn_mfma_f32_16x16x32_bf16(A8[ks], Bf[ks], acc, 0, 0, 0);
            #pragma unroll
            for (int r = 0; r < 4; ++r)
                rsum[rt][r] += fmaxf(acc[r] + bb, 0.f) * wo;
        }
    }

    #pragma unroll
    for (int off = 1; off < 16; off <<= 1)
        #pragma unroll
        for (int rt = 0; rt < 2; ++rt)
            #pragma unroll
            for (int r = 0; r < 4; ++r)
                rsum[rt][r] += __shfl_xor(rsum[rt][r], off);

    if (l16 == 0) {
        #pragma unroll
        for (int rt = 0; rt < 2; ++rt)
            #pragma unroll
            for (int r = 0; r < 4; ++r)
                partial[wave][rt * 16 + quad * 4 + r] = rsum[rt][r];
    }
    __syncthreads();

    if (tid < 32) {
        out[(size_t)batch * Tp + t0 + tid] =
            partial[0][tid] + partial[1][tid] + partial[2][tid]
          + partial[3][tid] + bout[0];
    }
}

extern "C" void kernel_launch(void* const* d_in, const int* in_sizes, int n_in,
                              void* d_out, int out_size, void* d_ws, size_t ws_size,
                              hipStream_t stream) {
    const float* state  = (const float*)d_in[0];
    const float* action = (const float*)d_in[1];
    const float* Wk     = (const float*)d_in[2];
    const float* Wq     = (const float*)d_in[3];
    const float* Wv     = (const float*)d_in[4];
    const float* W1     = (const float*)d_in[5];
    const float* b1     = (const float*)d_in[6];
    const float* W2     = (const float*)d_in[7];
    const float* b2     = (const float*)d_in[8];
    const float* Wout   = (const float*)d_in[9];
    const float* bout   = (const float*)d_in[10];
    float* out = (float*)d_out;

    char* ws = (char*)d_ws;
    unsigned short* W1b = (unsigned short*)(ws);           // 16 KB
    unsigned short* W2b = (unsigned short*)(ws + 16384);   // 128 KB

    prep_kernel<<<96, 256, 0, stream>>>(W1, W2, W1b, W2b);
    main_kernel<<<4 * Bp, 256, 0, stream>>>(state, action, Wk, Wq, Wv,
                                            W1b, W2b, b1, b2, Wout, bout, out);
}

// Round 13
// 96.310 us; speedup vs baseline: 1.1494x; 1.0652x over previous
//
#include <hip/hip_runtime.h>
#include <math.h>

#define Bp 256
#define Tp 128
#define SDp 8
#define ADp 2
#define Hp 3
#define Kp 4
#define HIDp 256
#define QDp (SDp + ADp)       // 10
#define X1Dp (Hp * Kp + QDp)  // 22  (row padded to 32 bf16 = 64 B)
#define QKLD 17               // qk row stride (floats)
#define LOG2E 1.4426950408889634f

typedef short bf16x8 __attribute__((ext_vector_type(8)));
typedef float f32x4  __attribute__((ext_vector_type(4)));

__device__ __forceinline__ unsigned short f2bf(float f) {
    unsigned u = __float_as_uint(f);
    unsigned r = (u + 0x7FFFu + ((u >> 16) & 1u)) >> 16;
    return (unsigned short)r;
}

// h1 LDS: row stride 512 B, XOR bits 4-6 with row&7 -> conflict-free b128 col reads
__device__ __forceinline__ unsigned h1_byte(int row, int colbytes) {
    return (((unsigned)row << 9) + (unsigned)colbytes) ^ ((unsigned)(row & 7) << 4);
}
// X1s LDS: row stride 64 B, XOR byte 4-5 with row bits 1-2 -> conflict-free b128 A reads
__device__ __forceinline__ unsigned x1_byte(int row, int colbytes) {
    return ((unsigned)row << 6) + ((unsigned)colbytes ^ (((unsigned)row & 6u) << 3));
}

// ---------------------------------------------------------------------------
// prep: one-time W1/W2 f32 -> bf16 (96 blocks).
// ---------------------------------------------------------------------------
__global__ __launch_bounds__(256) void prep_kernel(
    const float* __restrict__ W1, const float* __restrict__ W2,
    unsigned short* __restrict__ W1b, unsigned short* __restrict__ W2b)
{
    const int bid = blockIdx.x;
    const int tid = threadIdx.x;
    if (bid < 64) {                       // W2 -> bf16 (65536 elems)
        const int i = bid * 1024 + tid * 4;
        const float4 v = *(const float4*)(W2 + i);
        ushort4 o;
        o.x = f2bf(v.x); o.y = f2bf(v.y); o.z = f2bf(v.z); o.w = f2bf(v.w);
        *(ushort4*)(W2b + i) = o;
    } else {                              // W1 -> bf16, 32-col padded rows
        const int i = (bid - 64) * 256 + tid;   // 0..8191
        const int r = i >> 5, c = i & 31;
        W1b[i] = (c < X1Dp) ? f2bf(W1[r * X1Dp + c]) : (unsigned short)0;
    }
}

// ---------------------------------------------------------------------------
// main (fused): 1024 blocks x 256 threads (4 waves), 32 positions/block.
// Best-measured configuration (R6, 97.4 us):
//  - phase S: s4 staging || qkp precompute (global reads) || wv staging,
//    plus b1/b2/Wout -> LDS (no scalar global loads inside MFMA loops).
//  - phase A: 16-iter j-loop (jo 8-way), no max-shift, no j==t branch
//    (post-subtract e_tt at finalize); shfl_xor(1,2,4) combine.
//  - phase B: ALL 8 W1b B-frags preloaded, then MFMA chain (1 L2 latency).
//  - phase C: wave owns 64 cols; Bf[8] batch-loaded per col-group; A8
//    re-read from swizzled h1s per row-tile (VGPR slack for load pipelining).
// ---------------------------------------------------------------------------
__global__ __launch_bounds__(256, 4) void main_kernel(
    const float* __restrict__ state, const float* __restrict__ action,
    const float* __restrict__ Wk, const float* __restrict__ Wq,
    const float* __restrict__ Wv,
    const unsigned short* __restrict__ W1b, const unsigned short* __restrict__ W2b,
    const float* __restrict__ b1, const float* __restrict__ b2,
    const float* __restrict__ Wout, const float* __restrict__ bout,
    float* __restrict__ out)
{
    const int bid   = blockIdx.x;
    const int batch = bid >> 2;
    const int t0    = (bid & 3) * 32;
    const int tid   = threadIdx.x;
    const int lane  = tid & 63;
    const int wave  = tid >> 6;     // 0..3
    const int quad  = lane >> 4;
    const int l16   = lane & 15;
    const int t_loc = tid >> 3;     // 0..31
    const int jo    = tid & 7;      // 8-way j split
    const int t     = t0 + t_loc;

    __shared__ float4 s4[Tp];                                // 2 KB
    __shared__ float  wv[Hp * Kp * Kp];                      // 192 B
    __shared__ float  qk[32 * QKLD];                         // 2.1 KB
    __shared__ float  b1s[HIDp];                             // 1 KB
    __shared__ float  b2s[HIDp];                             // 1 KB
    __shared__ float  wouts[HIDp];                           // 1 KB
    __shared__ __align__(16) unsigned short X1s[32 * 32];    // 2 KB (swizzled)
    __shared__ __align__(16) unsigned short h1s[32 * 256];   // 16 KB (swizzled)
    __shared__ float partial[4][32];                         // 512 B

    // ---- phase S: parallel staging + per-t precompute ----
    if (tid < Tp) {
        s4[tid] = ((const float4*)(state + (size_t)batch * Tp * SDp))[tid * 2];
    } else if (tid < 160) {
        const int ta = tid - 128;           // 0..31
        const int tt = t0 + ta;
        float qs[QDp];
        {
            const float* srow = state + ((size_t)batch * Tp + tt) * SDp;
            const float4 v0 = *(const float4*)srow;
            const float4 v1 = *(const float4*)(srow + 4);
            qs[0]=v0.x; qs[1]=v0.y; qs[2]=v0.z; qs[3]=v0.w;
            qs[4]=v1.x; qs[5]=v1.y; qs[6]=v1.z; qs[7]=v1.w;
            const float* arow = action + ((size_t)batch * Tp + tt) * ADp;
            qs[8] = arow[0]; qs[9] = arow[1];
        }
        float q[Hp * Kp];
        #pragma unroll
        for (int r = 0; r < Hp * Kp; ++r) {
            float a = 0.f;
            #pragma unroll
            for (int d = 0; d < QDp; ++d) a += qs[d] * Wq[r * QDp + d];
            q[r] = a;
        }
        float* qrow = &qk[ta * QKLD];
        #pragma unroll
        for (int h = 0; h < Hp; ++h)
            #pragma unroll
            for (int c = 0; c < Kp; ++c) {
                float a = 0.f;
                #pragma unroll
                for (int k = 0; k < Kp; ++k) a += q[h * Kp + k] * Wk[(h * Kp + k) * Kp + c];
                qrow[h * 4 + c] = 0.5f * LOG2E * a;   // exp->exp2 fold; no max-shift
            }
        #pragma unroll
        for (int i = 0; i < 5; ++i) {
            const unsigned u = (unsigned)f2bf(qs[2*i]) | ((unsigned)f2bf(qs[2*i+1]) << 16);
            qrow[12 + i] = __uint_as_float(u);
        }
    } else if (tid < 160 + Hp * Kp * Kp) {
        wv[tid - 160] = Wv[tid - 160];
    }
    // biases/Wout -> LDS (coalesced, independent of branches above)
    b1s[tid]   = b1[tid];
    b2s[tid]   = b2[tid];
    wouts[tid] = Wout[tid];
    __syncthreads();

    // ---- phase A: j-loop (all 256 threads; 16 j's each) ----
    float rq[12];
    #pragma unroll
    for (int i = 0; i < 3; ++i)
        *(float4*)&rq[i * 4] = *(const float4*)&qk[t_loc * QKLD + i * 4];

    float l[Hp] = {0.f, 0.f, 0.f};
    float ac[Hp][4] = {};
    #pragma unroll
    for (int i = 0; i < 16; ++i) {
        const int j = (jo << 4) | ((i + jo) & 15);   // rotated: conflict-free banks
        const float4 sj = s4[j];
        #pragma unroll
        for (int h = 0; h < Hp; ++h) {
            const float d = sj.x * rq[h*4] + sj.y * rq[h*4+1]
                          + sj.z * rq[h*4+2] + sj.w * rq[h*4+3];
            const float e = __builtin_amdgcn_exp2f(d);   // no j==t branch
            l[h] += e;
            ac[h][0] += e * sj.x; ac[h][1] += e * sj.y;
            ac[h][2] += e * sj.z; ac[h][3] += e * sj.w;
        }
    }
    #pragma unroll
    for (int off = 1; off < 8; off <<= 1) {
        #pragma unroll
        for (int h = 0; h < Hp; ++h) {
            l[h] += __shfl_xor(l[h], off);
            #pragma unroll
            for (int c = 0; c < Kp; ++c) ac[h][c] += __shfl_xor(ac[h][c], off);
        }
    }

    if (jo == 0) {
        const float4 st = s4[t];
        unsigned short rowb[32] __attribute__((aligned(16)));
        #pragma unroll
        for (int h = 0; h < Hp; ++h) {
            // remove the j==t term: e_tt = exp2(dot(qkp_h, s_t))
            const float dtt = st.x * rq[h*4] + st.y * rq[h*4+1]
                            + st.z * rq[h*4+2] + st.w * rq[h*4+3];
            const float ett = __builtin_amdgcn_exp2f(dtt);
            const float inv = 1.f / (l[h] - ett);
            const float rb0 = (ac[h][0] - ett * st.x) * inv - st.x;
            const float rb1 = (ac[h][1] - ett * st.y) * inv - st.y;
            const float rb2 = (ac[h][2] - ett * st.z) * inv - st.z;
            const float rb3 = (ac[h][3] - ett * st.w) * inv - st.w;
            #pragma unroll
            for (int k = 0; k < Kp; ++k) {
                const int r = h * Kp + k;
                rowb[r] = f2bf(rb0 * wv[r*4] + rb1 * wv[r*4+1] + rb2 * wv[r*4+2] + rb3 * wv[r*4+3]);
            }
        }
        #pragma unroll
        for (int i = 0; i < 5; ++i) {
            const unsigned u = __float_as_uint(qk[t_loc * QKLD + 12 + i]);
            rowb[12 + 2*i] = (unsigned short)(u & 0xffffu);
            rowb[13 + 2*i] = (unsigned short)(u >> 16);
        }
        #pragma unroll
        for (int i = X1Dp; i < 32; ++i) rowb[i] = 0;

        const uint4* srcv = (const uint4*)rowb;
        #pragma unroll
        for (int i = 0; i < 4; ++i)
            *(uint4*)((char*)X1s + x1_byte(t_loc, i * 16)) = srcv[i];
    }
    __syncthreads();

    // ---- phase B: MLP1 (wave -> row-tile rt, col-half chh); B-frags batched ----
    {
        const int rt  = wave & 1;
        const int chh = wave >> 1;
        bf16x8 bfr[8];                       // ALL loads in flight before MFMA
        #pragma unroll
        for (int n = 0; n < 8; ++n)
            bfr[n] = *(const bf16x8*)&W1b[(chh * 128 + n * 16 + l16) * 32 + quad * 8];
        const bf16x8 afr = *(const bf16x8*)((const char*)X1s +
                             x1_byte(rt * 16 + l16, quad * 16));
        #pragma unroll
        for (int n = 0; n < 8; ++n) {
            const int col = chh * 128 + n * 16 + l16;
            f32x4 acc = {0.f, 0.f, 0.f, 0.f};
            acc = __builtin_amdgcn_mfma_f32_16x16x32_bf16(afr, bfr[n], acc, 0, 0, 0);
            const float bb = b1s[col];
            #pragma unroll
            for (int r = 0; r < 4; ++r) {
                const int row = rt * 16 + quad * 4 + r;
                *(unsigned short*)((char*)h1s + h1_byte(row, col * 2)) =
                    f2bf(fmaxf(acc[r] + bb, 0.f));
            }
        }
    }
    __syncthreads();

    // ---- phase C: MLP2 + out (wave owns cols [wave*64, wave*64+64)) ----
    float rsum[2][4] = {};
    #pragma unroll
    for (int i = 0; i < 4; ++i) {
        const int col = (wave * 4 + i) * 16 + l16;
        const unsigned short* wr = W2b + (size_t)col * HIDp + quad * 8;
        bf16x8 Bf[8];
        #pragma unroll
        for (int ks = 0; ks < 8; ++ks)
            Bf[ks] = *(const bf16x8*)(wr + ks * 32);
        const float bb = b2s[col];
        const float wo = wouts[col];
        #pragma unroll
        for (int rt = 0; rt < 2; ++rt) {
            bf16x8 A8[8];   // re-read per row-tile: VGPR slack for Bf pipelining
            #pragma unroll
            for (int ks = 0; ks < 8; ++ks)
                A8[ks] = *(const bf16x8*)((const char*)h1s +
                           h1_byte(rt * 16 + l16, ks * 64 + quad * 16));
            f32x4 acc = {0.f, 0.f, 0.f, 0.f};
            #pragma unroll
            for (int ks = 0; ks < 8; ++ks)
                acc = __builtin_amdgcn_mfma_f32_16x16x32_bf16(A8[ks], Bf[ks], acc, 0, 0, 0);
            #pragma unroll
            for (int r = 0; r < 4; ++r)
                rsum[rt][r] += fmaxf(acc[r] + bb, 0.f) * wo;
        }
    }

    #pragma unroll
    for (int off = 1; off < 16; off <<= 1)
        #pragma unroll
        for (int rt = 0; rt < 2; ++rt)
            #pragma unroll
            for (int r = 0; r < 4; ++r)
                rsum[rt][r] += __shfl_xor(rsum[rt][r], off);

    if (l16 == 0) {
        #pragma unroll
        for (int rt = 0; rt < 2; ++rt)
            #pragma unroll
            for (int r = 0; r < 4; ++r)
                partial[wave][rt * 16 + quad * 4 + r] = rsum[rt][r];
    }
    __syncthreads();

    if (tid < 32) {
        out[(size_t)batch * Tp + t0 + tid] =
            partial[0][tid] + partial[1][tid] + partial[2][tid]
          + partial[3][tid] + bout[0];
    }
}

extern "C" void kernel_launch(void* const* d_in, const int* in_sizes, int n_in,
                              void* d_out, int out_size, void* d_ws, size_t ws_size,
                              hipStream_t stream) {
    const float* state  = (const float*)d_in[0];
    const float* action = (const float*)d_in[1];
    const float* Wk     = (const float*)d_in[2];
    const float* Wq     = (const float*)d_in[3];
    const float* Wv     = (const float*)d_in[4];
    const float* W1     = (const float*)d_in[5];
    const float* b1     = (const float*)d_in[6];
    const float* W2     = (const float*)d_in[7];
    const float* b2     = (const float*)d_in[8];
    const float* Wout   = (const float*)d_in[9];
    const float* bout   = (const float*)d_in[10];
    float* out = (float*)d_out;

    char* ws = (char*)d_ws;
    unsigned short* W1b = (unsigned short*)(ws);           // 16 KB
    unsigned short* W2b = (unsigned short*)(ws + 16384);   // 128 KB

    prep_kernel<<<96, 256, 0, stream>>>(W1, W2, W1b, W2b);
    main_kernel<<<4 * Bp, 256, 0, stream>>>(state, action, Wk, Wq, Wv,
                                            W1b, W2b, b1, b2, Wout, bout, out);
}